// Round 6
// baseline (172344.519 us; speedup 1.0000x reference)
//
#include <hip/hip_runtime.h>

typedef __attribute__((ext_vector_type(4))) float f4;
using u32 = unsigned int;

constexpr int NB_ = 16;    // batch
constexpr int NS_ = 512;   // seq len
constexpr int ND_ = 1024;  // input dim
constexpr int NH_ = 512;   // hidden
constexpr int NSP_ = 8;    // speakers
constexpr int NH2_ = 256;  // head hidden
constexpr int HP = 516;    // padded fp32 LDS row

struct Params {
  const float *utt;
  const float *pg_wih, *pg_whh, *gg_wih, *gg_whh, *eg_wih, *eg_whh, *out_w1;
  const float *init_party, *init_emotion;
  const float *pg_bih, *pg_bhh, *gg_bih, *gg_bhh, *eg_bih, *eg_bhh;
  const float *ln_g, *ln_b, *out_b1, *out_ln_g, *out_ln_b, *out_w2, *out_b2;
  const int *spk;
  float *party_pre;  // [2][B][H] raw pg output (pre-LN), parity t&1
  float *g_new;      // [B][H]    raw gg output
  float *e_out;      // [2][B][H] raw eg output, parity t&1
  float *glob;       // [B][SP][H] post-LN (or raw init) global states
  float *h1buf;      // [B][H2] relu(e@W1+b1)
  double *sums;      // [3 groups][2 par][16 b][2] = 192 doubles (fp64 LN stats)
  u32 *bar;          // [counter, generation]
  float *out;        // [B][S]
};

__device__ __forceinline__ double sigm_d(double x) { return 1.0 / (1.0 + exp(-x)); }
__device__ __forceinline__ int sidx(int g, int par, int b, int c) {
  return ((g * 2 + par) * 16 + b) * 2 + c;
}

struct __align__(16) Smem {
  float hA[NB_][HP];            // operand 1 (LN'd party / glob row / LN'd emo)
  float hB[NB_][HP];            // operand 2 (eg: LN'd spk_state)
  double part[2][NB_][16][4];   // k-split partials {r, z, n, hn} (fp64)
  double stats[2][NB_][2];      // {mu, rstd} (fp64)
  int spk[NB_];
};

// device-scope generation barrier (80 blocks co-resident on 256 CUs)
__device__ __forceinline__ void gbar(u32* cnt, u32* gen, u32 nb) {
  __syncthreads();
  if (threadIdx.x == 0) {
    __threadfence();
    u32 g = __hip_atomic_load(gen, __ATOMIC_RELAXED, __HIP_MEMORY_SCOPE_AGENT);
    u32 a = __hip_atomic_fetch_add(cnt, 1u, __ATOMIC_ACQ_REL, __HIP_MEMORY_SCOPE_AGENT);
    if (a == nb - 1u) {
      __hip_atomic_store(cnt, 0u, __ATOMIC_RELAXED, __HIP_MEMORY_SCOPE_AGENT);
      __hip_atomic_fetch_add(gen, 1u, __ATOMIC_RELEASE, __HIP_MEMORY_SCOPE_AGENT);
    } else {
      while (__hip_atomic_load(gen, __ATOMIC_ACQUIRE, __HIP_MEMORY_SCOPE_AGENT) == g)
        __builtin_amdgcn_s_sleep(1);
    }
    __threadfence();
  }
  __syncthreads();
}

// dot of f4 vectors, accumulated exactly in fp64
__device__ __forceinline__ double dot4d(f4 a, f4 w) {
  return ((double)a.x * w.x + (double)a.y * w.y) + ((double)a.z * w.z + (double)a.w * w.w);
}

// phase A: party GRU (is_pg) or global GRU (!is_pg); jj0 = 16-col slice base.
__device__ void pg_gg_step(const Params& p, Smem& sm, int t, int jj0, bool is_pg) {
  const int tid = threadIdx.x;
  const float* wih = is_pg ? p.pg_wih : p.gg_wih;
  const float* whh = is_pg ? p.pg_whh : p.gg_whh;
  const float* bih = is_pg ? p.pg_bih : p.gg_bih;
  const float* bhh = is_pg ? p.pg_bhh : p.gg_bhh;
  const int g = is_pg ? 0 : 1;

  if (!is_pg) {
    if (tid < NB_) sm.spk[tid] = p.spk[tid * NS_ + t];
  } else if (t > 0 && tid < NB_) {
    double s = p.sums[sidx(0, (t - 1) & 1, tid, 0)];
    double q = p.sums[sidx(0, (t - 1) & 1, tid, 1)];
    double mu = s * (1.0 / NH_), var = q * (1.0 / NH_) - mu * mu;
    sm.stats[0][tid][0] = mu; sm.stats[0][tid][1] = 1.0 / sqrt(var + 1e-5);
  }
  __syncthreads();

  // stage h operand into LDS (fp32 values, LN applied in fp64)
  const float* prev = p.party_pre + (size_t)((t - 1) & 1) * NB_ * NH_;
  for (int idx = tid; idx < NB_ * NH_ / 4; idx += 512) {
    int b = idx >> 7, k = (idx & 127) * 4;
    f4 v;
    if (is_pg) {
      if (t == 0) v = *(const f4*)&p.init_party[k];
      else {
        f4 pv = *(const f4*)&prev[b * NH_ + k];
        f4 g4 = *(const f4*)&p.ln_g[k], b4 = *(const f4*)&p.ln_b[k];
        double mu = sm.stats[0][b][0], rs = sm.stats[0][b][1];
        v.x = (float)(((double)pv.x - mu) * rs * g4.x + b4.x);
        v.y = (float)(((double)pv.y - mu) * rs * g4.y + b4.y);
        v.z = (float)(((double)pv.z - mu) * rs * g4.z + b4.z);
        v.w = (float)(((double)pv.w - mu) * rs * g4.w + b4.w);
      }
    } else {
      v = *(const f4*)&p.glob[(size_t)(b * NSP_ + sm.spk[b]) * NH_ + k];
    }
    *(f4*)&sm.hA[b][k] = v;
  }
  __syncthreads();

  // partial dot products (fp64 accum): thread = (s=k-half, b, jj)
  {
    int s = tid >> 8, sub = tid & 255, b = sub >> 4, jj = sub & 15, j = jj0 + jj;
    const f4* x4 = (const f4*)(p.utt + (size_t)(b * NS_ + t) * ND_);
    const f4* h4 = (const f4*)&sm.hA[b][0];
    const f4* Wr = (const f4*)(wih + (size_t)j * 1536);
    const f4* Wz = (const f4*)(wih + (size_t)(NH_ + j) * 1536);
    const f4* Wn = (const f4*)(wih + (size_t)(2 * NH_ + j) * 1536);
    const f4* Hr = (const f4*)(whh + (size_t)j * 512);
    const f4* Hz = (const f4*)(whh + (size_t)(NH_ + j) * 512);
    const f4* Hn = (const f4*)(whh + (size_t)(2 * NH_ + j) * 512);
    double pr = 0, pz = 0, pn = 0, ph = 0;
    if (s == 0) {
      for (int k = 0; k < 128; ++k) {
        f4 a = x4[k];
        pr += dot4d(a, Wr[k]); pz += dot4d(a, Wz[k]); pn += dot4d(a, Wn[k]);
      }
      for (int k = 0; k < 128; ++k) {
        f4 a = h4[k];
        pr += dot4d(a, Hr[k]); pz += dot4d(a, Hz[k]); ph += dot4d(a, Hn[k]);
      }
    } else {
      const f4 *Wr2 = Wr + 256, *Wz2 = Wz + 256, *Wn2 = Wn + 256;
      for (int k = 128; k < 256; ++k) {
        f4 a = x4[k];
        pr += dot4d(a, Wr[k]); pz += dot4d(a, Wz[k]); pn += dot4d(a, Wn[k]);
      }
      for (int k = 0; k < 128; ++k) {
        f4 a = h4[k];
        pr += dot4d(a, Wr2[k]); pz += dot4d(a, Wz2[k]); pn += dot4d(a, Wn2[k]);
      }
    }
    sm.part[s][b][jj][0] = pr; sm.part[s][b][jj][1] = pz;
    sm.part[s][b][jj][2] = pn; sm.part[s][b][jj][3] = ph;
  }
  __syncthreads();

  // gate math (fp64), one thread per (b, jj)
  if (tid < 256) {
    int b = tid >> 4, jj = tid & 15, j = jj0 + jj;
    double r = sigm_d(sm.part[0][b][jj][0] + sm.part[1][b][jj][0] + (double)bih[j] + (double)bhh[j]);
    double z = sigm_d(sm.part[0][b][jj][1] + sm.part[1][b][jj][1] + (double)bih[NH_ + j] + (double)bhh[NH_ + j]);
    double inn = sm.part[0][b][jj][2] + sm.part[1][b][jj][2] + (double)bih[2 * NH_ + j];
    double hn  = sm.part[0][b][jj][3] + (double)bhh[2 * NH_ + j];
    double n = tanh(inn + r * hn);
    double hp = (double)sm.hA[b][j];  // the staged h IS the GRU hidden operand
    double hv = (1.0 - z) * n + z * hp;
    float* dst = is_pg ? (p.party_pre + (size_t)(t & 1) * NB_ * NH_) : p.g_new;
    dst[b * NH_ + j] = (float)hv;
    float hf = (float)hv;
    double s1 = (double)hf, s2 = (double)hf * (double)hf;
    for (int m = 8; m; m >>= 1) { s1 += __shfl_xor(s1, m); s2 += __shfl_xor(s2, m); }
    if (jj == 0) {
      atomicAdd(&p.sums[sidx(g, t & 1, b, 0)], s1);
      atomicAdd(&p.sums[sidx(g, t & 1, b, 1)], s2);
    }
  }
}

// phase B: emotion GRU
__device__ void eg_step(const Params& p, Smem& sm, int t, int jj0) {
  const int tid = threadIdx.x;
  if (t > 0 && tid < NB_) {
    double s = p.sums[sidx(2, (t - 1) & 1, tid, 0)];
    double q = p.sums[sidx(2, (t - 1) & 1, tid, 1)];
    double mu = s * (1.0 / NH_), var = q * (1.0 / NH_) - mu * mu;
    sm.stats[0][tid][0] = mu; sm.stats[0][tid][1] = 1.0 / sqrt(var + 1e-5);
  }
  if (tid >= NB_ && tid < 2 * NB_) {
    int b = tid - NB_;
    double s = p.sums[sidx(1, t & 1, b, 0)];
    double q = p.sums[sidx(1, t & 1, b, 1)];
    double mu = s * (1.0 / NH_), var = q * (1.0 / NH_) - mu * mu;
    sm.stats[1][b][0] = mu; sm.stats[1][b][1] = 1.0 / sqrt(var + 1e-5);
  }
  __syncthreads();
  const float* eprev = p.e_out + (size_t)((t - 1) & 1) * NB_ * NH_;
  for (int idx = tid; idx < NB_ * NH_ / 2; idx += 512) {
    int half = idx >= NB_ * NH_ / 4;
    int r4 = idx & (NB_ * NH_ / 4 - 1);
    int b = r4 >> 7, k = (r4 & 127) * 4;
    f4 g4 = *(const f4*)&p.ln_g[k], b4 = *(const f4*)&p.ln_b[k];
    if (!half) {
      f4 v;
      if (t == 0) v = *(const f4*)&p.init_emotion[k];
      else {
        f4 pv = *(const f4*)&eprev[b * NH_ + k];
        double mu = sm.stats[0][b][0], rs = sm.stats[0][b][1];
        v.x = (float)(((double)pv.x - mu) * rs * g4.x + b4.x);
        v.y = (float)(((double)pv.y - mu) * rs * g4.y + b4.y);
        v.z = (float)(((double)pv.z - mu) * rs * g4.z + b4.z);
        v.w = (float)(((double)pv.w - mu) * rs * g4.w + b4.w);
      }
      *(f4*)&sm.hA[b][k] = v;
    } else {
      f4 pv = *(const f4*)&p.g_new[b * NH_ + k];
      double mu = sm.stats[1][b][0], rs = sm.stats[1][b][1];
      f4 v;
      v.x = (float)(((double)pv.x - mu) * rs * g4.x + b4.x);
      v.y = (float)(((double)pv.y - mu) * rs * g4.y + b4.y);
      v.z = (float)(((double)pv.z - mu) * rs * g4.z + b4.z);
      v.w = (float)(((double)pv.w - mu) * rs * g4.w + b4.w);
      *(f4*)&sm.hB[b][k] = v;
    }
  }
  __syncthreads();
  {
    int s = tid >> 8, sub = tid & 255, b = sub >> 4, jj = sub & 15, j = jj0 + jj;
    const f4* A4 = (const f4*)&sm.hA[b][0];   // LN'd emo
    const f4* B4 = (const f4*)&sm.hB[b][0];   // LN'd spk_state
    const f4* Wr = (const f4*)(p.eg_wih + (size_t)j * 1024);
    const f4* Wz = (const f4*)(p.eg_wih + (size_t)(NH_ + j) * 1024);
    const f4* Wn = (const f4*)(p.eg_wih + (size_t)(2 * NH_ + j) * 1024);
    const f4* Hr = (const f4*)(p.eg_whh + (size_t)j * 512);
    const f4* Hz = (const f4*)(p.eg_whh + (size_t)(NH_ + j) * 512);
    const f4* Hn = (const f4*)(p.eg_whh + (size_t)(2 * NH_ + j) * 512);
    double pr = 0, pz = 0, pn = 0, ph = 0;
    if (s == 0) {
      for (int k = 0; k < 128; ++k) {
        f4 a = A4[k];
        pr += dot4d(a, Wr[k]); pz += dot4d(a, Wz[k]); pn += dot4d(a, Wn[k]);
        ph += dot4d(a, Hn[k]);
      }
    } else {
      const f4 *Wr2 = Wr + 128, *Wz2 = Wz + 128, *Wn2 = Wn + 128;
      for (int k = 0; k < 128; ++k) {
        f4 a = B4[k];
        pr += dot4d(a, Wr2[k]); pz += dot4d(a, Wz2[k]); pn += dot4d(a, Wn2[k]);
      }
      for (int k = 0; k < 128; ++k) {
        f4 a = A4[k];
        pr += dot4d(a, Hr[k]); pz += dot4d(a, Hz[k]);
      }
    }
    sm.part[s][b][jj][0] = pr; sm.part[s][b][jj][1] = pz;
    sm.part[s][b][jj][2] = pn; sm.part[s][b][jj][3] = ph;
  }
  __syncthreads();
  if (tid < 256) {
    int b = tid >> 4, jj = tid & 15, j = jj0 + jj;
    double r = sigm_d(sm.part[0][b][jj][0] + sm.part[1][b][jj][0] + (double)p.eg_bih[j] + (double)p.eg_bhh[j]);
    double z = sigm_d(sm.part[0][b][jj][1] + sm.part[1][b][jj][1] + (double)p.eg_bih[NH_ + j] + (double)p.eg_bhh[NH_ + j]);
    double inn = sm.part[0][b][jj][2] + sm.part[1][b][jj][2] + (double)p.eg_bih[2 * NH_ + j];
    double hn  = sm.part[0][b][jj][3] + (double)p.eg_bhh[2 * NH_ + j];
    double n = tanh(inn + r * hn);
    double hp = (double)sm.hA[b][j];
    double hv = (1.0 - z) * n + z * hp;
    float hf = (float)hv;
    p.e_out[(size_t)(t & 1) * NB_ * NH_ + b * NH_ + j] = hf;
    double s1 = (double)hf, s2 = (double)hf * (double)hf;
    for (int m = 8; m; m >>= 1) { s1 += __shfl_xor(s1, m); s2 += __shfl_xor(s2, m); }
    if (jj == 0) {
      atomicAdd(&p.sums[sidx(2, t & 1, b, 0)], s1);
      atomicAdd(&p.sums[sidx(2, t & 1, b, 1)], s2);
    }
  }
}

// phase B: glob[b][spk_t] <- LN(g_new); zero next-parity pg/gg sums
__device__ void wb_step(const Params& p, int t, int b) {
  const int tid = threadIdx.x;
  int spv = p.spk[b * NS_ + t];
  double s = p.sums[sidx(1, t & 1, b, 0)], q = p.sums[sidx(1, t & 1, b, 1)];
  double mu = s * (1.0 / NH_), var = q * (1.0 / NH_) - mu * mu, rs = 1.0 / sqrt(var + 1e-5);
  for (int k = tid; k < NH_; k += 512)
    p.glob[(size_t)(b * NSP_ + spv) * NH_ + k] =
        (float)(((double)p.g_new[b * NH_ + k] - mu) * rs * p.ln_g[k] + p.ln_b[k]);
  if (tid == 0) {
    int par = (t + 1) & 1;
    p.sums[sidx(0, par, b, 0)] = 0.0; p.sums[sidx(0, par, b, 1)] = 0.0;
    p.sums[sidx(1, par, b, 0)] = 0.0; p.sums[sidx(1, par, b, 1)] = 0.0;
  }
}

// phase A: h1[b][ct*16..+16] = relu(e_out(th) @ W1^T + b1), fp64 accum
__device__ void head_step(const Params& p, Smem& sm, int th, int ct) {
  const int tid = threadIdx.x;
  int s = tid >> 8, sub = tid & 255, b = sub >> 4, ci = sub & 15, c = ct * 16 + ci;
  const f4* er = (const f4*)(p.e_out + (size_t)(th & 1) * NB_ * NH_ + b * NH_);
  const f4* w = (const f4*)(p.out_w1 + (size_t)c * NH_);
  double acc = 0;
  for (int k = s * 64; k < s * 64 + 64; ++k) acc += dot4d(er[k], w[k]);
  sm.part[s][b][ci][0] = acc;
  __syncthreads();
  if (tid < 256) {
    double h1 = sm.part[0][b][ci][0] + sm.part[1][b][ci][0] + (double)p.out_b1[c];
    p.h1buf[b * NH2_ + c] = (float)fmax(h1, 0.0);
  }
}

// phase B: LN(h1) -> sigmoid(h1n @ w2 + b2) -> out[b][ts]
__device__ void score_step(const Params& p, int ts) {
  const int tid = threadIdx.x;
  if (tid >= 256) return;
  int b = tid >> 4, cg = tid & 15;
  double s1 = 0, s2 = 0;
  float hv[16];
#pragma unroll
  for (int i = 0; i < 16; ++i) {
    float v = p.h1buf[b * NH2_ + cg * 16 + i];
    hv[i] = v; s1 += (double)v; s2 += (double)v * (double)v;
  }
  for (int m = 8; m; m >>= 1) { s1 += __shfl_xor(s1, m); s2 += __shfl_xor(s2, m); }
  double mu = s1 * (1.0 / NH2_), var = s2 * (1.0 / NH2_) - mu * mu, rstd = 1.0 / sqrt(var + 1e-5);
  double d = 0;
#pragma unroll
  for (int i = 0; i < 16; ++i) {
    int c = cg * 16 + i;
    d += (((double)hv[i] - mu) * rstd * p.out_ln_g[c] + (double)p.out_ln_b[c]) * (double)p.out_w2[c];
  }
  for (int m = 8; m; m >>= 1) d += __shfl_xor(d, m);
  if (cg == 0) p.out[b * NS_ + ts] = (float)sigm_d(d + (double)p.out_b2[0]);
}

// Two barriers per step:
// phase A: pg(t) | gg(t) | head(t-1)+eg-sum-zero ; phase B: eg(t) | wb(t) | score(t-1)
__global__ __launch_bounds__(512) void seq_kernel(Params p) {
  __shared__ Smem sm;
  const int bid = blockIdx.x, tid = threadIdx.x;
  for (int t = 0; t < NS_; ++t) {
    if (bid < 32) {
      pg_gg_step(p, sm, t, bid * 16, true);
    } else if (bid < 64) {
      pg_gg_step(p, sm, t, (bid - 32) * 16, false);
    } else {
      if (bid == 64 && tid < 32) p.sums[sidx(2, t & 1, tid >> 1, tid & 1)] = 0.0;
      if (t > 0) head_step(p, sm, t - 1, bid - 64);
    }
    gbar(p.bar, p.bar + 1, gridDim.x);
    if (bid < 32) {
      eg_step(p, sm, t, bid * 16);
    } else if (bid < 48) {
      wb_step(p, t, bid - 32);
    } else if (bid == 48 && t > 0) {
      score_step(p, t - 1);
    }
    gbar(p.bar, p.bar + 1, gridDim.x);
  }
  if (bid >= 64) head_step(p, sm, NS_ - 1, bid - 64);
  gbar(p.bar, p.bar + 1, gridDim.x);
  if (bid == 48) score_step(p, NS_ - 1);
}

__global__ void init_kernel(float* glob, const float* init_global, double* sums, u32* bar) {
  long stride = (long)gridDim.x * blockDim.x;
  long t0 = (long)blockIdx.x * blockDim.x + threadIdx.x;
  for (long i = t0; i < (long)NB_ * NSP_ * NH_; i += stride) {
    int sp = ((int)i >> 9) & (NSP_ - 1);
    int k = (int)i & (NH_ - 1);
    glob[i] = init_global[sp * NH_ + k];
  }
  for (long i = t0; i < 192; i += stride) sums[i] = 0.0;
  if (t0 == 0) { bar[0] = 0u; bar[1] = 0u; }
}

extern "C" void kernel_launch(void* const* d_in, const int* in_sizes, int n_in,
                              void* d_out, int out_size, void* d_ws, size_t ws_size,
                              hipStream_t stream) {
  (void)in_sizes; (void)n_in; (void)out_size;
  Params p;
  p.utt    = (const float*)d_in[0];
  p.spk    = (const int*)d_in[1];
  p.init_party   = (const float*)d_in[2];
  const float* ig = (const float*)d_in[3];
  p.init_emotion = (const float*)d_in[4];
  p.pg_wih = (const float*)d_in[5];
  p.pg_whh = (const float*)d_in[6];
  p.pg_bih = (const float*)d_in[7];
  p.pg_bhh = (const float*)d_in[8];
  p.gg_wih = (const float*)d_in[9];
  p.gg_whh = (const float*)d_in[10];
  p.gg_bih = (const float*)d_in[11];
  p.gg_bhh = (const float*)d_in[12];
  p.eg_wih = (const float*)d_in[13];
  p.eg_whh = (const float*)d_in[14];
  p.eg_bih = (const float*)d_in[15];
  p.eg_bhh = (const float*)d_in[16];
  // 17..19 attention weights: softmax over length-1 axis == 1 -> provably unused
  p.ln_g   = (const float*)d_in[20];
  p.ln_b   = (const float*)d_in[21];
  p.out_w1 = (const float*)d_in[22];
  p.out_b1 = (const float*)d_in[23];
  p.out_ln_g = (const float*)d_in[24];
  p.out_ln_b = (const float*)d_in[25];
  p.out_w2 = (const float*)d_in[26];
  p.out_b2 = (const float*)d_in[27];

  char* w = (char*)d_ws;
  auto alloc = [&](size_t bytes) { char* r = w; w += (bytes + 255) & ~(size_t)255; return r; };
  float* party_pre = (float*)alloc((size_t)2 * NB_ * NH_ * 4);
  float* g_new     = (float*)alloc((size_t)NB_ * NH_ * 4);
  float* e_out     = (float*)alloc((size_t)2 * NB_ * NH_ * 4);
  float* glob      = (float*)alloc((size_t)NB_ * NSP_ * NH_ * 4);
  float* h1buf     = (float*)alloc((size_t)NB_ * NH2_ * 4);
  double* sums     = (double*)alloc(192 * 8);
  u32*   bar       = (u32*)alloc(256);
  if ((size_t)(w - (char*)d_ws) > ws_size) return;

  init_kernel<<<dim3(64), dim3(256), 0, stream>>>(glob, ig, sums, bar);

  p.party_pre = party_pre; p.g_new = g_new; p.e_out = e_out; p.glob = glob;
  p.h1buf = h1buf; p.sums = sums; p.bar = bar; p.out = (float*)d_out;

  seq_kernel<<<dim3(80), dim3(512), 0, stream>>>(p);
}